// Round 4
// baseline (414.603 us; speedup 1.0000x reference)
//
#include <hip/hip_runtime.h>

// loss = sum_{b,i,j} exp(-(g0^2/(2 s0^2) + g1^2/(2 s1^2))) * (z2[i]+z2[j]-2*zi.zj) / (B*T^2)
// Memory-bound on gt_dT (256 MB, read exactly once -> nontemporal).
//   prep:  z fp32 -> bf16 (4 MB, L2-resident) + row norms z2, zero out.
//   main:  per wave 32x32 Gram via mfma_f32_16x16x32_bf16 (frags from L2-resident
//          zbf), per-wave LDS re-layout (C/D layout -> stream layout), gt streamed
//          with prefetched nontemporal float4 loads (16 B/lane, 100% line use).

#define T_DIM 2048
#define D_DIM 128
#define B_DIM 8
#define NTHREADS 256
#define GSTRIDE 36   // 32x36 f32 per-wave gram tile: 2-way bank aliasing only (free)

typedef short s16x8 __attribute__((ext_vector_type(8)));
typedef float f32x4 __attribute__((ext_vector_type(4)));   // native vector: ok for nontemporal builtins

__device__ __forceinline__ unsigned short f2bf(float x) {
    unsigned int u = __float_as_uint(x);
    u += 0x7fffu + ((u >> 16) & 1u);   // round-to-nearest-even
    return (unsigned short)(u >> 16);
}

__global__ __launch_bounds__(NTHREADS)
void patch_prep(const float* __restrict__ z, unsigned short* __restrict__ zbf,
                float* __restrict__ z2, float* __restrict__ out) {
    if (blockIdx.x == 0 && threadIdx.x == 0) out[0] = 0.0f;
    const int row = blockIdx.x * 8 + (threadIdx.x >> 5);   // 8 rows / block
    const int c4  = threadIdx.x & 31;                      // 32 float4 per row
    float4 v = ((const float4*)(z + (size_t)row * D_DIM))[c4];
    ushort4 p;
    p.x = f2bf(v.x); p.y = f2bf(v.y); p.z = f2bf(v.z); p.w = f2bf(v.w);
    ((ushort4*)(zbf + (size_t)row * D_DIM))[c4] = p;
    float s = v.x*v.x + v.y*v.y + v.z*v.z + v.w*v.w;
    #pragma unroll
    for (int m = 16; m >= 1; m >>= 1) s += __shfl_xor(s, m);
    if (c4 == 0) z2[row] = s;
}

__global__ __launch_bounds__(NTHREADS)
void patch_loss_main(const unsigned short* __restrict__ zbf,
                     const float* __restrict__ z2,
                     const float* __restrict__ gt,
                     const float* __restrict__ sigma,
                     float* __restrict__ out) {
    __shared__ float gram[4][32][GSTRIDE];   // per-wave 32x32 Gram patch
    __shared__ float red[4];

    const int tid  = threadIdx.x;
    const int wave = tid >> 6;
    const int lane = tid & 63;
    const int c = lane & 15;     // fragment col (A/B row idx, C/D col)
    const int q = lane >> 4;     // k-group for A/B, row-group for C/D

    const int b  = blockIdx.z;
    const int i0 = blockIdx.y * 64 + (wave >> 1) * 32;   // wave's 32x32 patch
    const int j0 = blockIdx.x * 64 + (wave & 1) * 32;

    // ---- Prefetch gt: lane covers cols (j0+2c, j0+2c+1), rows i0 + fi*16 + q*4 + rr.
    //      Nontemporal: gt is single-use; keep zbf resident in L2.
    f32x4 g[8];
    const float* gbase = gt + ((size_t)b * T_DIM + i0 + q * 4) * (2 * T_DIM)
                            + (size_t)(j0 + 2 * c) * 2;
    #pragma unroll
    for (int fi = 0; fi < 2; ++fi)
        #pragma unroll
        for (int rr = 0; rr < 4; ++rr)
            g[fi * 4 + rr] = __builtin_nontemporal_load(
                (const f32x4*)(gbase + ((size_t)fi * 16 + rr) * (2 * T_DIM)));

    // ---- Gram: 2x2 fragments of 16x16, K = 128 = 4*32, frags direct from L2 ----
    const unsigned short* zi = zbf + ((size_t)b * T_DIM + i0) * D_DIM;
    const unsigned short* zj = zbf + ((size_t)b * T_DIM + j0) * D_DIM;
    f32x4 acc[2][2] = {};
    #pragma unroll
    for (int kk = 0; kk < 4; ++kk) {
        const int co = kk * 32 + q * 8;
        s16x8 fa0 = *(const s16x8*)(zi + (size_t)(c)      * D_DIM + co);
        s16x8 fa1 = *(const s16x8*)(zi + (size_t)(16 + c) * D_DIM + co);
        s16x8 fb0 = *(const s16x8*)(zj + (size_t)(c)      * D_DIM + co);
        s16x8 fb1 = *(const s16x8*)(zj + (size_t)(16 + c) * D_DIM + co);
        acc[0][0] = __builtin_amdgcn_mfma_f32_16x16x32_bf16(fa0, fb0, acc[0][0], 0, 0, 0);
        acc[0][1] = __builtin_amdgcn_mfma_f32_16x16x32_bf16(fa0, fb1, acc[0][1], 0, 0, 0);
        acc[1][0] = __builtin_amdgcn_mfma_f32_16x16x32_bf16(fa1, fb0, acc[1][0], 0, 0, 0);
        acc[1][1] = __builtin_amdgcn_mfma_f32_16x16x32_bf16(fa1, fb1, acc[1][1], 0, 0, 0);
    }

    // ---- Re-layout: C/D layout (col=c, row=q*4+r) -> LDS, then read stream layout ----
    #pragma unroll
    for (int fi = 0; fi < 2; ++fi)
        #pragma unroll
        for (int r = 0; r < 4; ++r) {
            gram[wave][fi * 16 + q * 4 + r][c]      = acc[fi][0][r];
            gram[wave][fi * 16 + q * 4 + r][16 + c] = acc[fi][1][r];
        }
    __syncthreads();   // drains lgkm (LDS writes) and vmcnt (gt prefetch landed)

    const float s0 = sigma[0], s1 = sigma[1];
    const float a0 = 0.5f / (s0 * s0);
    const float a1 = 0.5f / (s1 * s1);
    const float z2j0 = z2[(size_t)b * T_DIM + j0 + 2 * c];
    const float z2j1 = z2[(size_t)b * T_DIM + j0 + 2 * c + 1];

    // ---- Combine: lane (q,c) handles cols (2c, 2c+1), rows fi*16 + q*4 + rr ----
    float facc = 0.0f;
    #pragma unroll
    for (int fi = 0; fi < 2; ++fi)
        #pragma unroll
        for (int rr = 0; rr < 4; ++rr) {
            const int il = fi * 16 + q * 4 + rr;
            const float zzi = z2[(size_t)b * T_DIM + i0 + il];
            float2 s = *(const float2*)&gram[wave][il][2 * c];
            f32x4 gv = g[fi * 4 + rr];
            const float t0 = gv[0] * gv[0] * a0 + gv[1] * gv[1] * a1;
            const float t1 = gv[2] * gv[2] * a0 + gv[3] * gv[3] * a1;
            facc += __expf(-t0) * (zzi + z2j0 - 2.0f * s.x)
                  + __expf(-t1) * (zzi + z2j1 - 2.0f * s.y);
        }

    // ---- reduce + atomic ----
    #pragma unroll
    for (int m = 32; m >= 1; m >>= 1) facc += __shfl_xor(facc, m);
    if (lane == 0) red[wave] = facc;
    __syncthreads();
    if (tid == 0) {
        const float scale = 1.0f / ((float)B_DIM * (float)T_DIM * (float)T_DIM);
        atomicAdd(out, (red[0] + red[1] + red[2] + red[3]) * scale);
    }
}

extern "C" void kernel_launch(void* const* d_in, const int* in_sizes, int n_in,
                              void* d_out, int out_size, void* d_ws, size_t ws_size,
                              hipStream_t stream) {
    const float* z     = (const float*)d_in[0];
    const float* gt    = (const float*)d_in[1];
    const float* sigma = (const float*)d_in[2];
    float* out = (float*)d_out;

    unsigned short* zbf = (unsigned short*)d_ws;                          // 4 MB
    float* z2 = (float*)((char*)d_ws + (size_t)B_DIM * T_DIM * D_DIM * 2); // 64 KB

    patch_prep<<<(B_DIM * T_DIM) / 8, NTHREADS, 0, stream>>>(z, zbf, z2, out);
    dim3 grid(T_DIM / 64, T_DIM / 64, B_DIM);
    patch_loss_main<<<grid, NTHREADS, 0, stream>>>(zbf, z2, gt, sigma, out);
}

// Round 6
// 360.450 us; speedup vs baseline: 1.1502x; 1.1502x over previous
//
#include <hip/hip_runtime.h>

// loss = sum_{b,i,j} exp(-(g0^2/(2 s0^2) + g1^2/(2 s1^2))) * (z2[i]+z2[j]-2*zi.zj) / (B*T^2)
// Memory-bound on gt_dT (256 MB, single-use -> nontemporal).
//   prep:  z fp32 -> bf16 (4 MB, L2-resident) + row norms z2, zero out.
//   main:  128x128 tile / block, 4 waves = 4 i-bands of 32 rows, j-loop of 4
//          32-col subtiles. zi MFMA fragments held in registers across the
//          j-loop. Per-wave Gram re-layout through wave-private LDS (no
//          block barrier). Load order zj -> gt(nt) -> MFMA so the in-order
//          vmcnt wait for zj leaves the gt stream in flight under compute.

#define T_DIM 2048
#define D_DIM 128
#define B_DIM 8
#define NTHREADS 256
#define GSTRIDE 36   // 32x36 f32 per-wave gram tile: 2-way bank aliasing only (free)

typedef short s16x8 __attribute__((ext_vector_type(8)));
typedef float f32x4 __attribute__((ext_vector_type(4)));   // native vector: ok for nontemporal builtins

__device__ __forceinline__ unsigned short f2bf(float x) {
    unsigned int u = __float_as_uint(x);
    u += 0x7fffu + ((u >> 16) & 1u);   // round-to-nearest-even
    return (unsigned short)(u >> 16);
}

__global__ __launch_bounds__(NTHREADS)
void patch_prep(const float* __restrict__ z, unsigned short* __restrict__ zbf,
                float* __restrict__ z2, float* __restrict__ out) {
    if (blockIdx.x == 0 && threadIdx.x == 0) out[0] = 0.0f;
    const int row = blockIdx.x * 8 + (threadIdx.x >> 5);   // 8 rows / block
    const int c4  = threadIdx.x & 31;                      // 32 float4 per row
    float4 v = ((const float4*)(z + (size_t)row * D_DIM))[c4];
    ushort4 p;
    p.x = f2bf(v.x); p.y = f2bf(v.y); p.z = f2bf(v.z); p.w = f2bf(v.w);
    ((ushort4*)(zbf + (size_t)row * D_DIM))[c4] = p;
    float s = v.x*v.x + v.y*v.y + v.z*v.z + v.w*v.w;
    #pragma unroll
    for (int m = 16; m >= 1; m >>= 1) s += __shfl_xor(s, m);
    if (c4 == 0) z2[row] = s;
}

__global__ __launch_bounds__(NTHREADS)
void patch_loss_main(const unsigned short* __restrict__ zbf,
                     const float* __restrict__ z2,
                     const float* __restrict__ gt,
                     const float* __restrict__ sigma,
                     float* __restrict__ out) {
    __shared__ float gram[4][32][GSTRIDE];   // wave-private 32x32 Gram patch
    __shared__ float red[4];

    const int tid  = threadIdx.x;
    const int wave = tid >> 6;
    const int lane = tid & 63;
    const int c = lane & 15;     // fragment col (A/B row idx, C/D col)
    const int q = lane >> 4;     // k-group for A/B, row-group for C/D

    const int b     = blockIdx.z;
    const int i0    = blockIdx.y * 128 + wave * 32;   // wave's 32-row i-band
    const int jbase = blockIdx.x * 128;

    const float s0 = sigma[0], s1 = sigma[1];
    const float a0 = 0.5f / (s0 * s0);
    const float a1 = 0.5f / (s1 * s1);

    // ---- zi fragments: registers for the whole j-loop (32 VGPR) ----
    const unsigned short* zi = zbf + ((size_t)b * T_DIM + i0) * D_DIM;
    s16x8 fa[2][4];
    #pragma unroll
    for (int kk = 0; kk < 4; ++kk) {
        const int co = kk * 32 + q * 8;
        fa[0][kk] = *(const s16x8*)(zi + (size_t)(c)      * D_DIM + co);
        fa[1][kk] = *(const s16x8*)(zi + (size_t)(16 + c) * D_DIM + co);
    }
    // per-lane z2 for the 8 output rows this lane owns (C/D row = fi*16+q*4+rr)
    float z2i[2][4];
    #pragma unroll
    for (int fi = 0; fi < 2; ++fi)
        #pragma unroll
        for (int rr = 0; rr < 4; ++rr)
            z2i[fi][rr] = z2[(size_t)b * T_DIM + i0 + fi * 16 + q * 4 + rr];

    float facc = 0.0f;
    #pragma unroll
    for (int jj = 0; jj < 4; ++jj) {
        const int j0 = jbase + jj * 32;

        // zj fragments FIRST (newer-is-later: MFMA's vmcnt wait on these
        // leaves the gt loads below still in flight)
        const unsigned short* zj = zbf + ((size_t)b * T_DIM + j0) * D_DIM;
        s16x8 fb0[4], fb1[4];
        #pragma unroll
        for (int kk = 0; kk < 4; ++kk) {
            const int co = kk * 32 + q * 8;
            fb0[kk] = *(const s16x8*)(zj + (size_t)(c)      * D_DIM + co);
            fb1[kk] = *(const s16x8*)(zj + (size_t)(16 + c) * D_DIM + co);
        }

        // gt stream for this subtile: lane (q,c) covers cols (j0+2c, j0+2c+1),
        // rows i0 + fi*16 + q*4 + rr. Nontemporal: single-use, keep L2 for zbf.
        f32x4 g[8];
        const float* gbase = gt + ((size_t)b * T_DIM + i0 + q * 4) * (2 * T_DIM)
                                + (size_t)(j0 + 2 * c) * 2;
        #pragma unroll
        for (int fi = 0; fi < 2; ++fi)
            #pragma unroll
            for (int rr = 0; rr < 4; ++rr)
                g[fi * 4 + rr] = __builtin_nontemporal_load(
                    (const f32x4*)(gbase + ((size_t)fi * 16 + rr) * (2 * T_DIM)));

        // ---- Gram: 2x2 fragments of 16x16, K = 128 = 4*32 ----
        f32x4 acc[2][2] = {};
        #pragma unroll
        for (int kk = 0; kk < 4; ++kk) {
            acc[0][0] = __builtin_amdgcn_mfma_f32_16x16x32_bf16(fa[0][kk], fb0[kk], acc[0][0], 0, 0, 0);
            acc[0][1] = __builtin_amdgcn_mfma_f32_16x16x32_bf16(fa[0][kk], fb1[kk], acc[0][1], 0, 0, 0);
            acc[1][0] = __builtin_amdgcn_mfma_f32_16x16x32_bf16(fa[1][kk], fb0[kk], acc[1][0], 0, 0, 0);
            acc[1][1] = __builtin_amdgcn_mfma_f32_16x16x32_bf16(fa[1][kk], fb1[kk], acc[1][1], 0, 0, 0);
        }

        // ---- wave-private re-layout: C/D (col=c,row=q*4+r) -> stream layout.
        //      No block barrier needed: this wave only touches gram[wave];
        //      compiler-inserted lgkmcnt orders write->read within the wave.
        #pragma unroll
        for (int fi = 0; fi < 2; ++fi)
            #pragma unroll
            for (int r = 0; r < 4; ++r) {
                gram[wave][fi * 16 + q * 4 + r][c]      = acc[fi][0][r];
                gram[wave][fi * 16 + q * 4 + r][16 + c] = acc[fi][1][r];
            }

        const float z2j0 = z2[(size_t)b * T_DIM + j0 + 2 * c];
        const float z2j1 = z2[(size_t)b * T_DIM + j0 + 2 * c + 1];

        // ---- combine: lane (q,c) handles cols (2c,2c+1), rows fi*16+q*4+rr ----
        #pragma unroll
        for (int fi = 0; fi < 2; ++fi)
            #pragma unroll
            for (int rr = 0; rr < 4; ++rr) {
                const int il = fi * 16 + q * 4 + rr;
                float2 s = *(const float2*)&gram[wave][il][2 * c];
                f32x4 gv = g[fi * 4 + rr];
                const float t0 = gv[0] * gv[0] * a0 + gv[1] * gv[1] * a1;
                const float t1 = gv[2] * gv[2] * a0 + gv[3] * gv[3] * a1;
                facc += __expf(-t0) * (z2i[fi][rr] + z2j0 - 2.0f * s.x)
                      + __expf(-t1) * (z2i[fi][rr] + z2j1 - 2.0f * s.y);
            }
    }

    // ---- reduce + atomic ----
    #pragma unroll
    for (int m = 32; m >= 1; m >>= 1) facc += __shfl_xor(facc, m);
    if (lane == 0) red[wave] = facc;
    __syncthreads();
    if (tid == 0) {
        const float scale = 1.0f / ((float)B_DIM * (float)T_DIM * (float)T_DIM);
        atomicAdd(out, (red[0] + red[1] + red[2] + red[3]) * scale);
    }
}

extern "C" void kernel_launch(void* const* d_in, const int* in_sizes, int n_in,
                              void* d_out, int out_size, void* d_ws, size_t ws_size,
                              hipStream_t stream) {
    const float* z     = (const float*)d_in[0];
    const float* gt    = (const float*)d_in[1];
    const float* sigma = (const float*)d_in[2];
    float* out = (float*)d_out;

    unsigned short* zbf = (unsigned short*)d_ws;                          // 4 MB
    float* z2 = (float*)((char*)d_ws + (size_t)B_DIM * T_DIM * D_DIM * 2); // 64 KB

    patch_prep<<<(B_DIM * T_DIM) / 8, NTHREADS, 0, stream>>>(z, zbf, z2, out);
    dim3 grid(T_DIM / 128, T_DIM / 128, B_DIM);
    patch_loss_main<<<grid, NTHREADS, 0, stream>>>(zbf, z2, gt, sigma, out);
}